// Round 4
// baseline (22.404 us; speedup 1.0000x reference)
//
#include <hip/hip_runtime.h>

#define B_DIM 32
#define O_DIM 1000
#define M_DIM 100
#define F_DIM 32
#define DS 6
#define DD 3
#define SEG 25      // o-segments per batch
#define CHUNK 40    // O_DIM / SEG
#define OSUB 8      // o-subgroups per block (lane-adjacent -> shuffle reduce)
#define TRIPS 5     // CHUNK / OSUB
#define MT 25       // m-tile per gat_final block

// Kernel 1: per (batch, o-segment) block computes partial softmax sums per m-column.
// partial layout: [B][SEG][M][8]  (0=denom, 1=sum p*pt, 2..7=sum p*raw_opes[o,d])
__global__ __launch_bounds__(256) void gat_partial(
    const float* __restrict__ raw_opes,   // [B,O,DS]
    const float* __restrict__ raw_mas,    // [B,M,DD]
    const float* __restrict__ proc_time,  // [B,O,M]
    const int*   __restrict__ adj,        // [Btot,O,M]
    const int*   __restrict__ bidx,       // [B]
    const float* __restrict__ Wsrc,       // [DS,F]
    const float* __restrict__ Wdst,       // [DD,F]
    const float* __restrict__ Wedge,      // [F]
    const float* __restrict__ attn_l,     // [F]
    const float* __restrict__ attn_r,     // [F]
    float* __restrict__ partial)
{
    const int b   = blockIdx.x / SEG;
    const int seg = blockIdx.x % SEG;
    const int t   = threadIdx.x;
    const int o0  = seg * CHUNK;

    __shared__ float ro_s[CHUNK * DS];   // 960 B — only LDS in this kernel

    // Stage this segment's raw_opes (240 floats). Issue loads first.
    const float* rop = raw_opes + ((size_t)b * O_DIM + o0) * DS;
    if (t < CHUNK * DS) ro_s[t] = rop[t];

    // Folded weights (uniform across block; overlaps staging latency).
    float wl[DS] = {0, 0, 0, 0, 0, 0};
    float we = 0.f;
    for (int f = 0; f < F_DIM; ++f) {
        float al = attn_l[f];
        we = fmaf(Wedge[f], al, we);
        #pragma unroll
        for (int d = 0; d < DS; ++d) wl[d] = fmaf(Wsrc[d * F_DIM + f], al, wl[d]);
    }
    float wr[DD] = {0, 0, 0};
    for (int f = 0; f < F_DIM; ++f) {
        float ar = attn_r[f];
        #pragma unroll
        for (int d = 0; d < DD; ++d) wr[d] = fmaf(Wdst[d * F_DIM + f], ar, wr[d]);
    }
    __syncthreads();

    if (t < 25 * OSUB) {
        const int mg = t / OSUB;   // 0..24: group of 4 consecutive m
        const int g  = t % OSUB;   // 0..7: o-subgroup, lane-adjacent

        const float* rm = raw_mas + ((size_t)b * M_DIM + mg * 4) * DD;
        float4 er;
        er.x = fmaf(rm[0], wr[0], fmaf(rm[1],  wr[1], rm[2]  * wr[2]));
        er.y = fmaf(rm[3], wr[0], fmaf(rm[4],  wr[1], rm[5]  * wr[2]));
        er.z = fmaf(rm[6], wr[0], fmaf(rm[7],  wr[1], rm[8]  * wr[2]));
        er.w = fmaf(rm[9], wr[0], fmaf(rm[10], wr[1], rm[11] * wr[2]));

        const float* ptp = proc_time + ((size_t)b * O_DIM + o0) * M_DIM + mg * 4;
        const int*   adp = adj + ((size_t)bidx[b] * O_DIM + o0) * M_DIM + mg * 4;

        float4 den = make_float4(0, 0, 0, 0), spa = make_float4(0, 0, 0, 0);
        float4 sd[DS];
        #pragma unroll
        for (int d = 0; d < DS; ++d) sd[d] = make_float4(0, 0, 0, 0);

        #pragma unroll
        for (int k = 0; k < TRIPS; ++k) {
            const int row = g + k * OSUB;
            float4 pt = *(const float4*)(ptp + row * M_DIM);
            int4   av = *(const int4*)(adp + row * M_DIM);
            float ro[DS];
            #pragma unroll
            for (int d = 0; d < DS; ++d) ro[d] = ro_s[row * DS + d];
            float elr = 0.f;
            #pragma unroll
            for (int d = 0; d < DS; ++d) elr = fmaf(ro[d], wl[d], elr);

            float s0 = elr + er.x + we * pt.x;
            float s1 = elr + er.y + we * pt.y;
            float s2 = elr + er.z + we * pt.z;
            float s3 = elr + er.w + we * pt.w;
            s0 = fmaxf(s0, 0.2f * s0); s1 = fmaxf(s1, 0.2f * s1);
            s2 = fmaxf(s2, 0.2f * s2); s3 = fmaxf(s3, 0.2f * s3);
            float p0 = (av.x == 1) ? __expf(s0) : 0.f;
            float p1 = (av.y == 1) ? __expf(s1) : 0.f;
            float p2 = (av.z == 1) ? __expf(s2) : 0.f;
            float p3 = (av.w == 1) ? __expf(s3) : 0.f;
            den.x += p0; den.y += p1; den.z += p2; den.w += p3;
            spa.x = fmaf(p0, pt.x, spa.x); spa.y = fmaf(p1, pt.y, spa.y);
            spa.z = fmaf(p2, pt.z, spa.z); spa.w = fmaf(p3, pt.w, spa.w);
            #pragma unroll
            for (int d = 0; d < DS; ++d) {
                sd[d].x = fmaf(p0, ro[d], sd[d].x);
                sd[d].y = fmaf(p1, ro[d], sd[d].y);
                sd[d].z = fmaf(p2, ro[d], sd[d].z);
                sd[d].w = fmaf(p3, ro[d], sd[d].w);
            }
        }

        // In-wave butterfly over the 8 lane-adjacent o-subgroups.
        #pragma unroll
        for (int s = 1; s < OSUB; s <<= 1) {
            den.x += __shfl_xor(den.x, s); den.y += __shfl_xor(den.y, s);
            den.z += __shfl_xor(den.z, s); den.w += __shfl_xor(den.w, s);
            spa.x += __shfl_xor(spa.x, s); spa.y += __shfl_xor(spa.y, s);
            spa.z += __shfl_xor(spa.z, s); spa.w += __shfl_xor(spa.w, s);
            #pragma unroll
            for (int d = 0; d < DS; ++d) {
                sd[d].x += __shfl_xor(sd[d].x, s); sd[d].y += __shfl_xor(sd[d].y, s);
                sd[d].z += __shfl_xor(sd[d].z, s); sd[d].w += __shfl_xor(sd[d].w, s);
            }
        }

        if (g == 0) {
            float* dst = partial + (((size_t)b * SEG + seg) * M_DIM + mg * 4) * 8;
            *(float4*)(dst + 0)  = make_float4(den.x, spa.x, sd[0].x, sd[1].x);
            *(float4*)(dst + 4)  = make_float4(sd[2].x, sd[3].x, sd[4].x, sd[5].x);
            *(float4*)(dst + 8)  = make_float4(den.y, spa.y, sd[0].y, sd[1].y);
            *(float4*)(dst + 12) = make_float4(sd[2].y, sd[3].y, sd[4].y, sd[5].y);
            *(float4*)(dst + 16) = make_float4(den.z, spa.z, sd[0].z, sd[1].z);
            *(float4*)(dst + 20) = make_float4(sd[2].z, sd[3].z, sd[4].z, sd[5].z);
            *(float4*)(dst + 24) = make_float4(den.w, spa.w, sd[0].w, sd[1].w);
            *(float4*)(dst + 28) = make_float4(sd[2].w, sd[3].w, sd[4].w, sd[5].w);
        }
    }
}

// Kernel 2: reduce segments, normalize, emit sigmoid output. Grid = B*4.
__global__ __launch_bounds__(256) void gat_final(
    const float* __restrict__ raw_mas,    // [B,M,DD]
    const float* __restrict__ Wsrc,       // [DS,F]
    const float* __restrict__ Wdst,       // [DD,F]
    const float* __restrict__ Wedge,      // [F]
    const float* __restrict__ attn_r,     // [F]
    const float* __restrict__ partial,
    float* __restrict__ out)              // [B,M,F]
{
    const int b  = blockIdx.x >> 2;
    const int m0 = (blockIdx.x & 3) * MT;
    const int t  = threadIdx.x;

    __shared__ float smd[MT][9];   // +1 pad

    if (t < MT * 8) {
        const int ml = t % MT;     // consecutive lanes -> consecutive m
        const int k  = t / MT;     // partial slot 0..7
        const float* p = partial + (((size_t)b * SEG) * M_DIM + m0 + ml) * 8 + k;
        float acc = 0.f;
        #pragma unroll
        for (int s = 0; s < SEG; ++s) acc += p[(size_t)s * M_DIM * 8];
        smd[ml][k] = acc;
    }
    __syncthreads();

    if (t < MT) {
        float wr[DD] = {0, 0, 0};
        for (int f = 0; f < F_DIM; ++f) {
            float ar = attn_r[f];
            #pragma unroll
            for (int d = 0; d < DD; ++d) wr[d] = fmaf(Wdst[d * F_DIM + f], ar, wr[d]);
        }
        const float* rm = raw_mas + ((size_t)b * M_DIM + m0 + t) * DD;
        float er = fmaf(rm[0], wr[0], fmaf(rm[1], wr[1], rm[2] * wr[2]));
        float skk = 2.f * er;
        skk = fmaxf(skk, 0.2f * skk);
        float pkk = __expf(skk);
        float den = smd[t][0], spa = smd[t][1];
        float s0 = smd[t][2], s1 = smd[t][3], s2 = smd[t][4],
              s3 = smd[t][5], s4 = smd[t][6], s5 = smd[t][7];
        float inv = 1.f / (den + pkk);
        smd[t][0] = s0 * inv; smd[t][1] = s1 * inv; smd[t][2] = s2 * inv;
        smd[t][3] = s3 * inv; smd[t][4] = s4 * inv; smd[t][5] = s5 * inv;
        smd[t][6] = spa * inv;
        smd[t][7] = pkk * inv;
    }
    __syncthreads();

    for (int idx = t; idx < MT * F_DIM; idx += 256) {
        const int ml = idx >> 5;
        const int f  = idx & 31;
        float v = smd[ml][6] * Wedge[f];
        #pragma unroll
        for (int d = 0; d < DS; ++d) v = fmaf(smd[ml][d], Wsrc[d * F_DIM + f], v);
        const float* rm = raw_mas + ((size_t)b * M_DIM + m0 + ml) * DD;
        float fd = 0.f;
        #pragma unroll
        for (int d = 0; d < DD; ++d) fd = fmaf(rm[d], Wdst[d * F_DIM + f], fd);
        v = fmaf(fd, smd[ml][7], v);
        out[((size_t)b * M_DIM + m0 + ml) * F_DIM + f] = 1.f / (1.f + __expf(-v));
    }
}

extern "C" void kernel_launch(void* const* d_in, const int* in_sizes, int n_in,
                              void* d_out, int out_size, void* d_ws, size_t ws_size,
                              hipStream_t stream) {
    const float* raw_opes  = (const float*)d_in[0];
    const float* raw_mas   = (const float*)d_in[1];
    const float* proc_time = (const float*)d_in[2];
    const int*   adj       = (const int*)d_in[3];
    const int*   bidx      = (const int*)d_in[4];
    const float* Wsrc      = (const float*)d_in[5];
    const float* Wdst      = (const float*)d_in[6];
    const float* Wedge     = (const float*)d_in[7];
    const float* attn_l    = (const float*)d_in[8];
    const float* attn_r    = (const float*)d_in[9];
    float* out     = (float*)d_out;
    float* partial = (float*)d_ws;   // 32*25*100*8*4 = 2.56 MB

    gat_partial<<<B_DIM * SEG, 256, 0, stream>>>(raw_opes, raw_mas, proc_time, adj, bidx,
                                                 Wsrc, Wdst, Wedge, attn_l, attn_r, partial);
    gat_final<<<B_DIM * 4, 256, 0, stream>>>(raw_mas, Wsrc, Wdst, Wedge, attn_r, partial, out);
}

// Round 5
// 19.099 us; speedup vs baseline: 1.1730x; 1.1730x over previous
//
#include <hip/hip_runtime.h>

#define B_DIM 32
#define O_DIM 1000
#define M_DIM 100
#define F_DIM 32
#define DS 6
#define DD 3
#define SEG 25      // o-segments per batch
#define CHUNK 40    // O_DIM / SEG
#define OSUB 10     // o-subgroups per block
#define TRIPS 4     // CHUNK / OSUB
#define MT 25       // m-tile per gat_final block

// Kernel 1: per (batch, o-segment) block computes partial softmax sums per m-column.
// partial layout: [B][SEG][M][8]  (0=denom, 1=sum p*pt, 2..7=sum p*raw_opes[o,d])
__global__ __launch_bounds__(256) void gat_partial(
    const float* __restrict__ raw_opes,   // [B,O,DS]
    const float* __restrict__ raw_mas,    // [B,M,DD]
    const float* __restrict__ proc_time,  // [B,O,M]
    const int*   __restrict__ adj,        // [Btot,O,M]
    const int*   __restrict__ bidx,       // [B]
    const float* __restrict__ Wsrc,       // [DS,F]
    const float* __restrict__ Wdst,       // [DD,F]
    const float* __restrict__ Wedge,      // [F]
    const float* __restrict__ attn_l,     // [F]
    const float* __restrict__ attn_r,     // [F]
    float* __restrict__ partial)
{
    const int b   = blockIdx.x / SEG;
    const int seg = blockIdx.x % SEG;
    const int t   = threadIdx.x;
    const int o0  = seg * CHUNK;

    __shared__ float ro_s[CHUNK * DS];
    __shared__ float part_s[OSUB][M_DIM][9];   // +1 pad

    // Stage this segment's raw_opes (240 floats).
    const float* rop = raw_opes + ((size_t)b * O_DIM + o0) * DS;
    if (t < CHUNK * DS) ro_s[t] = rop[t];

    // Folded weights (uniform; overlaps staging latency).
    float wl[DS] = {0, 0, 0, 0, 0, 0};
    float we = 0.f;
    for (int f = 0; f < F_DIM; ++f) {
        float al = attn_l[f];
        we = fmaf(Wedge[f], al, we);
        #pragma unroll
        for (int d = 0; d < DS; ++d) wl[d] = fmaf(Wsrc[d * F_DIM + f], al, wl[d]);
    }
    float wr[DD] = {0, 0, 0};
    for (int f = 0; f < F_DIM; ++f) {
        float ar = attn_r[f];
        #pragma unroll
        for (int d = 0; d < DD; ++d) wr[d] = fmaf(Wdst[d * F_DIM + f], ar, wr[d]);
    }
    __syncthreads();

    if (t < 25 * OSUB) {
        const int mg = t % 25;   // consecutive lanes -> consecutive m (coalesced)
        const int g  = t / 25;   // o-subgroup

        const float* ptp = proc_time + ((size_t)b * O_DIM + o0) * M_DIM + mg * 4;
        const int*   adp = adj + ((size_t)bidx[b] * O_DIM + o0) * M_DIM + mg * 4;

        // Prefetch ALL trips' loads back-to-back: 8 outstanding 16B loads/thread.
        float4 pt[TRIPS];
        int4   av[TRIPS];
        #pragma unroll
        for (int k = 0; k < TRIPS; ++k) {
            const int row = g + k * OSUB;
            pt[k] = *(const float4*)(ptp + row * M_DIM);
            av[k] = *(const int4*)(adp + row * M_DIM);
        }

        const float* rm = raw_mas + ((size_t)b * M_DIM + mg * 4) * DD;
        float4 er;
        er.x = fmaf(rm[0], wr[0], fmaf(rm[1],  wr[1], rm[2]  * wr[2]));
        er.y = fmaf(rm[3], wr[0], fmaf(rm[4],  wr[1], rm[5]  * wr[2]));
        er.z = fmaf(rm[6], wr[0], fmaf(rm[7],  wr[1], rm[8]  * wr[2]));
        er.w = fmaf(rm[9], wr[0], fmaf(rm[10], wr[1], rm[11] * wr[2]));

        float4 den = make_float4(0, 0, 0, 0), spa = make_float4(0, 0, 0, 0);
        float4 sd[DS];
        #pragma unroll
        for (int d = 0; d < DS; ++d) sd[d] = make_float4(0, 0, 0, 0);

        #pragma unroll
        for (int k = 0; k < TRIPS; ++k) {
            const int row = g + k * OSUB;
            float ro[DS];
            #pragma unroll
            for (int d = 0; d < DS; ++d) ro[d] = ro_s[row * DS + d];
            float elr = 0.f;
            #pragma unroll
            for (int d = 0; d < DS; ++d) elr = fmaf(ro[d], wl[d], elr);

            float s0 = elr + er.x + we * pt[k].x;
            float s1 = elr + er.y + we * pt[k].y;
            float s2 = elr + er.z + we * pt[k].z;
            float s3 = elr + er.w + we * pt[k].w;
            s0 = fmaxf(s0, 0.2f * s0); s1 = fmaxf(s1, 0.2f * s1);
            s2 = fmaxf(s2, 0.2f * s2); s3 = fmaxf(s3, 0.2f * s3);
            float p0 = (av[k].x == 1) ? __expf(s0) : 0.f;
            float p1 = (av[k].y == 1) ? __expf(s1) : 0.f;
            float p2 = (av[k].z == 1) ? __expf(s2) : 0.f;
            float p3 = (av[k].w == 1) ? __expf(s3) : 0.f;
            den.x += p0; den.y += p1; den.z += p2; den.w += p3;
            spa.x = fmaf(p0, pt[k].x, spa.x); spa.y = fmaf(p1, pt[k].y, spa.y);
            spa.z = fmaf(p2, pt[k].z, spa.z); spa.w = fmaf(p3, pt[k].w, spa.w);
            #pragma unroll
            for (int d = 0; d < DS; ++d) {
                sd[d].x = fmaf(p0, ro[d], sd[d].x);
                sd[d].y = fmaf(p1, ro[d], sd[d].y);
                sd[d].z = fmaf(p2, ro[d], sd[d].z);
                sd[d].w = fmaf(p3, ro[d], sd[d].w);
            }
        }

        #pragma unroll
        for (int j = 0; j < 4; ++j) {
            const int m = mg * 4 + j;
            float* ps = part_s[g][m];
            ps[0] = j == 0 ? den.x : j == 1 ? den.y : j == 2 ? den.z : den.w;
            ps[1] = j == 0 ? spa.x : j == 1 ? spa.y : j == 2 ? spa.z : spa.w;
            #pragma unroll
            for (int d = 0; d < DS; ++d)
                ps[2 + d] = j == 0 ? sd[d].x : j == 1 ? sd[d].y : j == 2 ? sd[d].z : sd[d].w;
        }
    }
    __syncthreads();

    // Reduce over OSUB groups and write [m][8] partials.
    if (t < 2 * M_DIM) {
        const int m = t % M_DIM, half = t / M_DIM;
        float a[4] = {0, 0, 0, 0};
        #pragma unroll
        for (int g = 0; g < OSUB; ++g) {
            #pragma unroll
            for (int k = 0; k < 4; ++k) a[k] += part_s[g][m][half * 4 + k];
        }
        *(float4*)(partial + (((size_t)b * SEG + seg) * M_DIM + m) * 8 + half * 4) =
            make_float4(a[0], a[1], a[2], a[3]);
    }
}

// Kernel 2: reduce segments, normalize, emit sigmoid output. Grid = B*4.
__global__ __launch_bounds__(256) void gat_final(
    const float* __restrict__ raw_mas,    // [B,M,DD]
    const float* __restrict__ Wsrc,       // [DS,F]
    const float* __restrict__ Wdst,       // [DD,F]
    const float* __restrict__ Wedge,      // [F]
    const float* __restrict__ attn_r,     // [F]
    const float* __restrict__ partial,
    float* __restrict__ out)              // [B,M,F]
{
    const int b  = blockIdx.x >> 2;
    const int m0 = (blockIdx.x & 3) * MT;
    const int t  = threadIdx.x;

    __shared__ float smd[MT][9];

    if (t < MT * 8) {
        const int ml = t % MT;
        const int k  = t / MT;
        const float* p = partial + (((size_t)b * SEG) * M_DIM + m0 + ml) * 8 + k;
        float acc = 0.f;
        #pragma unroll
        for (int s = 0; s < SEG; ++s) acc += p[(size_t)s * M_DIM * 8];
        smd[ml][k] = acc;
    }
    __syncthreads();

    if (t < MT) {
        float wr[DD] = {0, 0, 0};
        for (int f = 0; f < F_DIM; ++f) {
            float ar = attn_r[f];
            #pragma unroll
            for (int d = 0; d < DD; ++d) wr[d] = fmaf(Wdst[d * F_DIM + f], ar, wr[d]);
        }
        const float* rm = raw_mas + ((size_t)b * M_DIM + m0 + t) * DD;
        float er = fmaf(rm[0], wr[0], fmaf(rm[1], wr[1], rm[2] * wr[2]));
        float skk = 2.f * er;
        skk = fmaxf(skk, 0.2f * skk);
        float pkk = __expf(skk);
        float den = smd[t][0], spa = smd[t][1];
        float s0 = smd[t][2], s1 = smd[t][3], s2 = smd[t][4],
              s3 = smd[t][5], s4 = smd[t][6], s5 = smd[t][7];
        float inv = 1.f / (den + pkk);
        smd[t][0] = s0 * inv; smd[t][1] = s1 * inv; smd[t][2] = s2 * inv;
        smd[t][3] = s3 * inv; smd[t][4] = s4 * inv; smd[t][5] = s5 * inv;
        smd[t][6] = spa * inv;
        smd[t][7] = pkk * inv;
    }
    __syncthreads();

    for (int idx = t; idx < MT * F_DIM; idx += 256) {
        const int ml = idx >> 5;
        const int f  = idx & 31;
        float v = smd[ml][6] * Wedge[f];
        #pragma unroll
        for (int d = 0; d < DS; ++d) v = fmaf(smd[ml][d], Wsrc[d * F_DIM + f], v);
        const float* rm = raw_mas + ((size_t)b * M_DIM + m0 + ml) * DD;
        float fd = 0.f;
        #pragma unroll
        for (int d = 0; d < DD; ++d) fd = fmaf(rm[d], Wdst[d * F_DIM + f], fd);
        v = fmaf(fd, smd[ml][7], v);
        out[((size_t)b * M_DIM + m0 + ml) * F_DIM + f] = 1.f / (1.f + __expf(-v));
    }
}

extern "C" void kernel_launch(void* const* d_in, const int* in_sizes, int n_in,
                              void* d_out, int out_size, void* d_ws, size_t ws_size,
                              hipStream_t stream) {
    const float* raw_opes  = (const float*)d_in[0];
    const float* raw_mas   = (const float*)d_in[1];
    const float* proc_time = (const float*)d_in[2];
    const int*   adj       = (const int*)d_in[3];
    const int*   bidx      = (const int*)d_in[4];
    const float* Wsrc      = (const float*)d_in[5];
    const float* Wdst      = (const float*)d_in[6];
    const float* Wedge     = (const float*)d_in[7];
    const float* attn_l    = (const float*)d_in[8];
    const float* attn_r    = (const float*)d_in[9];
    float* out     = (float*)d_out;
    float* partial = (float*)d_ws;   // 32*25*100*8*4 = 2.56 MB

    gat_partial<<<B_DIM * SEG, 256, 0, stream>>>(raw_opes, raw_mas, proc_time, adj, bidx,
                                                 Wsrc, Wdst, Wedge, attn_l, attn_r, partial);
    gat_final<<<B_DIM * 4, 256, 0, stream>>>(raw_mas, Wsrc, Wdst, Wedge, attn_r, partial, out);
}